// Round 18
// baseline (709.302 us; speedup 1.0000x reference)
//
#include <hip/hip_runtime.h>
#include <hip/hip_bf16.h>

#define HW 112
#define NPIX (HW*HW)            // 12544
#define NTOK_TOTAL (16*NPIX)    // 200704
#define SCALE_ATTN 0.17677669529663689f

typedef short bf16x8 __attribute__((ext_vector_type(8)));
typedef float f32x4 __attribute__((ext_vector_type(4)));

__device__ __forceinline__ short f2bf(float f) {
    __hip_bfloat16 h = __float2bfloat16(f);
    return *reinterpret_cast<short*>(&h);
}

// tanh-form GELU: x * sigmoid(1.5957691*x + 0.0713548*x^3); |err| ~3e-4
__device__ __forceinline__ float gelu_tanh(float x) {
    float t  = x * x;
    float m1 = fmaf(0.071354816f, t, 1.5957691f);
    float e  = __expf(x * m1);
    float r  = __builtin_amdgcn_rcpf(e + 1.0f);
    return fmaf(-x, r, x);
}

// async global->LDS, 16B per lane; lds dest must be wave-uniform base
__device__ __forceinline__ void gload_lds16(const short* g, short* l) {
    __builtin_amdgcn_global_load_lds(
        (__attribute__((address_space(1))) void*)g,
        (__attribute__((address_space(3))) void*)l,
        16, 0, 0);
}

// ---------------- patch merging: x (16,3,448,448) -> xp (16,112,112,96) ----
// v1 (known good): one block per 16 output pixels.
__global__ __launch_bounds__(256) void patch_merge_kernel(
    const float* __restrict__ x, const float* __restrict__ pm_w,
    const float* __restrict__ pm_b, float* __restrict__ xp)
{
    __shared__ float w_lds[48*96];
    __shared__ float in_lds[16*52];
    __shared__ float b_lds[96];
    const int t = threadIdx.x;
    const int jt = blockIdx.x, i = blockIdx.y, b = blockIdx.z;
    const int j0 = jt * 16;

    for (int e = t; e < 48*96; e += 256) w_lds[e] = pm_w[e];
    if (t < 96) b_lds[t] = pm_b[t];
    for (int e = t; e < 768; e += 256) {
        int r = e >> 6, col = e & 63;
        int c = r >> 2, kh = r & 3;
        float v = x[(((size_t)(b*3 + c))*448 + (4*i + kh))*448 + 4*j0 + col];
        in_lds[(col >> 2)*52 + c*16 + kh*4 + (col & 3)] = v;
    }
    __syncthreads();
    for (int e = t; e < 16*96; e += 256) {
        int pos = e / 96, ch = e % 96;
        float acc = b_lds[ch];
        #pragma unroll
        for (int k = 0; k < 48; ++k)
            acc = fmaf(in_lds[pos*52 + k], w_lds[k*96 + ch], acc);
        xp[((size_t)((b*HW + i)*HW) + j0 + pos)*96 + ch] = acc;
    }
}

// ------------- weight prep -------------------------------------------------
// FF weights -> fragment-ordered wF[2][4][ W1c(9216) | W2c(9216) ]
// qkvT [2][288][96] (q cols pre-scaled by SCALE_ATTN), outT [2][96][96]
__global__ __launch_bounds__(256) void prep_weights_kernel(
    const float* __restrict__ ff1, const float* __restrict__ ff2,
    const float* __restrict__ qkv_w, const float* __restrict__ out_w,
    short* __restrict__ wF,
    short* __restrict__ qkvT, short* __restrict__ outT)
{
    int i = blockIdx.x * 256 + threadIdx.x;
    if (i < 147456) {
        int l = i / 73728, r = i % 73728;
        int c = r / 18432, r2 = r % 18432;
        int half = r2 / 9216, r3 = r2 % 9216;
        int f = r3 / 512, L = (r3 % 512) / 8, j = r3 % 8;
        int ks = f / 6, n = f % 6;
        float val;
        if (half == 0) {
            int k  = ks*32 + (L >> 4)*8 + j;       // 0..95
            int ng = c*96 + n*16 + (L & 15);       // 0..383
            val = ff1[(size_t)l*36864 + (size_t)k*384 + ng];
        } else {
            int kg = c*96 + ks*32 + (L >> 4)*8 + j; // 0..383
            int ng = n*16 + (L & 15);               // 0..95
            val = ff2[(size_t)l*36864 + (size_t)kg*96 + ng];
        }
        wF[i] = f2bf(val);
    } else if (i < 202752) {
        int j = i - 147456;
        int l = j / 27648, r = j % 27648, n = r / 96, k = r % 96;
        float v = qkv_w[(size_t)l*27648 + k*288 + n];
        if (n < 96) v *= SCALE_ATTN;   // fold attention scale into W_q
        qkvT[j] = f2bf(v);
    } else if (i < 221184) {
        int j = i - 202752;
        int l = j / 9216, r = j % 9216, n = r / 96, k = r % 96;
        outT[j] = f2bf(out_w[(size_t)l*9216 + k*96 + n]);
    }
}

// ---- fused LN1 + qkv + window attention + out-proj + residual (bf16 MFMA) --
// r10 schedule; LDS diet: P overwrites q|k in qk_s (in-wave), V held in regs
// across B2 then vT -> bufA (y dead), O -> bufA after B3.
// LDS ~43.3KB -> 3 blocks/CU.
template<bool SHIFTED>
__global__ __launch_bounds__(192) void attn_mfma_kernel(
    float* __restrict__ xp,
    const float* __restrict__ ln_g, const float* __restrict__ ln_b,
    const short* __restrict__ qkvT,
    const float* __restrict__ pos_tab,
    const short* __restrict__ outT,
    const float* __restrict__ out_b)
{
    __shared__ short bufA[6912];     // y[64][104] -> vT[3][32][72] -> O[64][104]
    __shared__ short qk_s[13824];    // [h][64][72]: q|k -> P (own-head, own-wave)
    __shared__ float pos_l[169];
    __shared__ float ob_s[96];
    __shared__ float lng[96], lnb[96];

    const int t = threadIdx.x;
    const int lane = t & 63;
    const int h = t >> 6;
    const int l15 = lane & 15, lhi = lane >> 4;
    const int wh = blockIdx.x >> 4, ww = blockIdx.x & 15;
    const int b = blockIdx.y;
    const int SH = SHIFTED ? 3 : 0;

    if (t < 169) pos_l[t] = pos_tab[t];
    if (t < 96) { lng[t] = ln_g[t]; lnb[t] = ln_b[t]; ob_s[t] = out_b[t]; }
    __syncthreads();   // B0

    // ---- phase 0: gather (shift folded) + register LN -> y bf16 in bufA ----
    {
        const int part = t & 3;
        for (int row = t >> 2; row < 49; row += 48) {
            int ti = (row*37) >> 8, tj = row - ti*7;
            int gi = wh*7 + ti + SH; if (gi >= HW) gi -= HW;
            int gj = ww*7 + tj + SH; if (gj >= HW) gj -= HW;
            const float* src = xp + ((size_t)((b*HW + gi)*HW + gj))*96 + part*24;
            float v[24];
            #pragma unroll
            for (int q4 = 0; q4 < 6; ++q4) {
                float4 vv = *reinterpret_cast<const float4*>(src + q4*4);
                v[q4*4+0]=vv.x; v[q4*4+1]=vv.y; v[q4*4+2]=vv.z; v[q4*4+3]=vv.w;
            }
            float s = 0.f, s2 = 0.f;
            #pragma unroll
            for (int j = 0; j < 24; ++j) { s += v[j]; s2 += v[j]*v[j]; }
            s  += __shfl_xor(s, 1);  s  += __shfl_xor(s, 2);
            s2 += __shfl_xor(s2, 1); s2 += __shfl_xor(s2, 2);
            float mu = s * (1.f/96.f);
            float var = s2 * (1.f/96.f) - mu*mu;
            float rs = rsqrtf(var + 1e-5f);
            unsigned* yw = reinterpret_cast<unsigned*>(bufA) + row*52 + part*12;
            #pragma unroll
            for (int j = 0; j < 12; ++j) {
                int c = part*24 + 2*j;
                float lo = (v[2*j]   - mu)*rs*lng[c]   + lnb[c];
                float hi = (v[2*j+1] - mu)*rs*lng[c+1] + lnb[c+1];
                yw[j] = (unsigned)(unsigned short)f2bf(lo) |
                        ((unsigned)(unsigned short)f2bf(hi) << 16);
            }
        }
        for (int e = t; e < 15*52; e += 192)
            reinterpret_cast<unsigned*>(bufA)[(49 + e/52)*52 + e%52] = 0u;
    }
    __syncthreads();   // B1: y ready

    // ---- phase 1: q,k,v for this wave's head (72 MFMA); v kept in regs ----
    f32x4 vv[2][4];
    {
        f32x4 qk[2][2][4];
        #pragma unroll
        for (int p = 0; p < 2; ++p)
            #pragma unroll
            for (int s = 0; s < 2; ++s)
                #pragma unroll
                for (int m = 0; m < 4; ++m)
                    { qk[p][s][m][0]=0.f; qk[p][s][m][1]=0.f; qk[p][s][m][2]=0.f; qk[p][s][m][3]=0.f; }
        #pragma unroll
        for (int s = 0; s < 2; ++s)
            #pragma unroll
            for (int m = 0; m < 4; ++m)
                { vv[s][m][0]=0.f; vv[s][m][1]=0.f; vv[s][m][2]=0.f; vv[s][m][3]=0.f; }
        #pragma unroll
        for (int ks = 0; ks < 3; ++ks) {
            bf16x8 a[4];
            #pragma unroll
            for (int m = 0; m < 4; ++m)
                a[m] = *reinterpret_cast<const bf16x8*>(&bufA[(m*16 + l15)*104 + ks*32 + lhi*8]);
            #pragma unroll
            for (int p = 0; p < 2; ++p)
                #pragma unroll
                for (int s = 0; s < 2; ++s) {
                    bf16x8 bf = *reinterpret_cast<const bf16x8*>(
                        qkvT + (p*96 + h*32 + s*16 + l15)*96 + ks*32 + lhi*8);
                    #pragma unroll
                    for (int m = 0; m < 4; ++m)
                        qk[p][s][m] = __builtin_amdgcn_mfma_f32_16x16x32_bf16(
                            a[m], bf, qk[p][s][m], 0, 0, 0);
                }
            #pragma unroll
            for (int s = 0; s < 2; ++s) {
                bf16x8 bf = *reinterpret_cast<const bf16x8*>(
                    qkvT + (192 + h*32 + s*16 + l15)*96 + ks*32 + lhi*8);
                #pragma unroll
                for (int m = 0; m < 4; ++m)
                    vv[s][m] = __builtin_amdgcn_mfma_f32_16x16x32_bf16(
                        a[m], bf, vv[s][m], 0, 0, 0);
            }
        }
        #pragma unroll
        for (int p = 0; p < 2; ++p)
            #pragma unroll
            for (int s = 0; s < 2; ++s)
                #pragma unroll
                for (int m = 0; m < 4; ++m)
                    #pragma unroll
                    for (int r = 0; r < 4; ++r)
                        qk_s[h*4608 + (m*16 + lhi*4 + r)*72 + p*32 + s*16 + l15] =
                            f2bf(qk[p][s][m][r]);
    }
    __syncthreads();   // B2: all y reads done (bufA -> vT)

    // vT -> bufA (own-head region; same wave reads it in phase 3)
    #pragma unroll
    for (int s = 0; s < 2; ++s)
        #pragma unroll
        for (int m = 0; m < 4; ++m)
            #pragma unroll
            for (int r = 0; r < 4; ++r)
                bufA[h*2304 + (s*16 + l15)*72 + m*16 + lhi*4 + r] = f2bf(vv[s][m][r]);

    // ---- phase 2: S = QK^T + pos (+mask), softmax, P -> qk_s (over q|k) ----
    float pv[4][4][4];
    {
        f32x4 sacc[4][4];
        #pragma unroll
        for (int m = 0; m < 4; ++m)
            #pragma unroll
            for (int n = 0; n < 4; ++n)
                { sacc[m][n][0]=0.f; sacc[m][n][1]=0.f; sacc[m][n][2]=0.f; sacc[m][n][3]=0.f; }
        bf16x8 aq[4], bk[4];
        #pragma unroll
        for (int m = 0; m < 4; ++m)
            aq[m] = *reinterpret_cast<const bf16x8*>(&qk_s[h*4608 + (m*16 + l15)*72 + lhi*8]);
        #pragma unroll
        for (int n = 0; n < 4; ++n)
            bk[n] = *reinterpret_cast<const bf16x8*>(&qk_s[h*4608 + (n*16 + l15)*72 + 32 + lhi*8]);
        #pragma unroll
        for (int m = 0; m < 4; ++m)
            #pragma unroll
            for (int n = 0; n < 4; ++n)
                sacc[m][n] = __builtin_amdgcn_mfma_f32_16x16x32_bf16(aq[m], bk[n], sacc[m][n], 0, 0, 0);

        #pragma unroll
        for (int m = 0; m < 4; ++m)
            #pragma unroll
            for (int n = 0; n < 4; ++n)
                #pragma unroll
                for (int r = 0; r < 4; ++r) {
                    int i = m*16 + lhi*4 + r, j = n*16 + l15;
                    float v;
                    if (i >= 49 || j >= 49) v = -1e30f;
                    else {
                        int xi = (i*37) >> 8, yi = i - xi*7;
                        int xj = (j*37) >> 8, yj = j - xj*7;
                        v = sacc[m][n][r] + pos_l[(xj - xi + 6)*13 + (yj - yi + 6)];
                        if (SHIFTED) {
                            if (wh == 15 && ((xi >= 4) != (xj >= 4))) v = -1e30f;
                            if (ww == 15 && ((yi >= 4) != (yj >= 4))) v = -1e30f;
                        }
                    }
                    pv[m][n][r] = v;
                }
    }
    #pragma unroll
    for (int m = 0; m < 4; ++m)
        #pragma unroll
        for (int r = 0; r < 4; ++r) {
            float mx = fmaxf(fmaxf(pv[m][0][r], pv[m][1][r]), fmaxf(pv[m][2][r], pv[m][3][r]));
            mx = fmaxf(mx, __shfl_xor(mx, 1)); mx = fmaxf(mx, __shfl_xor(mx, 2));
            mx = fmaxf(mx, __shfl_xor(mx, 4)); mx = fmaxf(mx, __shfl_xor(mx, 8));
            float e0 = __expf(pv[m][0][r] - mx), e1 = __expf(pv[m][1][r] - mx);
            float e2 = __expf(pv[m][2][r] - mx), e3 = __expf(pv[m][3][r] - mx);
            float s = e0 + e1 + e2 + e3;
            s += __shfl_xor(s, 1); s += __shfl_xor(s, 2);
            s += __shfl_xor(s, 4); s += __shfl_xor(s, 8);
            float inv = 1.f / s;
            pv[m][0][r] = e0*inv; pv[m][1][r] = e1*inv;
            pv[m][2][r] = e2*inv; pv[m][3][r] = e3*inv;
        }
    #pragma unroll
    for (int m = 0; m < 4; ++m)
        #pragma unroll
        for (int n = 0; n < 4; ++n)
            #pragma unroll
            for (int r = 0; r < 4; ++r)
                qk_s[h*4608 + (m*16 + lhi*4 + r)*72 + n*16 + l15] = f2bf(pv[m][n][r]);

    // ---- phase 3: O = P @ V (16 MFMA; all own-head regions) ----
    f32x4 oacc[2][4];
    #pragma unroll
    for (int n = 0; n < 2; ++n)
        #pragma unroll
        for (int m = 0; m < 4; ++m)
            { oacc[n][m][0]=0.f; oacc[n][m][1]=0.f; oacc[n][m][2]=0.f; oacc[n][m][3]=0.f; }
    #pragma unroll
    for (int ks = 0; ks < 2; ++ks) {
        bf16x8 ap[4], bv[2];
        #pragma unroll
        for (int m = 0; m < 4; ++m)
            ap[m] = *reinterpret_cast<const bf16x8*>(&qk_s[h*4608 + (m*16 + l15)*72 + ks*32 + lhi*8]);
        #pragma unroll
        for (int n = 0; n < 2; ++n)
            bv[n] = *reinterpret_cast<const bf16x8*>(&bufA[h*2304 + (n*16 + l15)*72 + ks*32 + lhi*8]);
        #pragma unroll
        for (int n = 0; n < 2; ++n)
            #pragma unroll
            for (int m = 0; m < 4; ++m)
                oacc[n][m] = __builtin_amdgcn_mfma_f32_16x16x32_bf16(ap[m], bv[n], oacc[n][m], 0, 0, 0);
    }
    __syncthreads();   // B3: all vT reads done (bufA -> O)
    #pragma unroll
    for (int n = 0; n < 2; ++n)
        #pragma unroll
        for (int m = 0; m < 4; ++m)
            #pragma unroll
            for (int r = 0; r < 4; ++r)
                bufA[(m*16 + lhi*4 + r)*104 + h*32 + n*16 + l15] = f2bf(oacc[n][m][r]);
    __syncthreads();   // B4: O assembled cross-head

    // ---- phase 4: out-proj (24 MFMA) + bias + residual scatter ----
    {
        f32x4 pacc[2][4];
        #pragma unroll
        for (int n = 0; n < 2; ++n)
            #pragma unroll
            for (int m = 0; m < 4; ++m)
                { pacc[n][m][0]=0.f; pacc[n][m][1]=0.f; pacc[n][m][2]=0.f; pacc[n][m][3]=0.f; }
        #pragma unroll
        for (int ks = 0; ks < 3; ++ks) {
            bf16x8 ao[4], bw[2];
            #pragma unroll
            for (int m = 0; m < 4; ++m)
                ao[m] = *reinterpret_cast<const bf16x8*>(&bufA[(m*16 + l15)*104 + ks*32 + lhi*8]);
            #pragma unroll
            for (int n = 0; n < 2; ++n)
                bw[n] = *reinterpret_cast<const bf16x8*>(
                    outT + ((h*2 + n)*16 + l15)*96 + ks*32 + lhi*8);
            #pragma unroll
            for (int n = 0; n < 2; ++n)
                #pragma unroll
                for (int m = 0; m < 4; ++m)
                    pacc[n][m] = __builtin_amdgcn_mfma_f32_16x16x32_bf16(ao[m], bw[n], pacc[n][m], 0, 0, 0);
        }
        #pragma unroll
        for (int m = 0; m < 4; ++m)
            #pragma unroll
            for (int r = 0; r < 4; ++r) {
                int tok = m*16 + lhi*4 + r;
                if (tok < 49) {
                    int ti = (tok*37) >> 8, tj = tok - ti*7;
                    int gi = wh*7 + ti + SH; if (gi >= HW) gi -= HW;
                    int gj = ww*7 + tj + SH; if (gj >= HW) gj -= HW;
                    float* dst = xp + ((size_t)((b*HW + gi)*HW + gj))*96;
                    #pragma unroll
                    for (int n = 0; n < 2; ++n) {
                        int ch = (h*2 + n)*16 + l15;
                        dst[ch] += pacc[n][m][r] + ob_s[ch];
                    }
                }
            }
    }
}

// ------------- fused LN2 + FF1 + GELU + FF2 + residual (bf16 MFMA v7) ------
// 4 waves / 128 tokens; split staging (waves 0-1 own W1, waves 2-3 own W2),
// W2 double-buffered; all DMA overlapped under compute (T3/T4-min).
__global__ __launch_bounds__(256) void ff_mfma_kernel(
    float* __restrict__ xp,
    const float* __restrict__ ln_g, const float* __restrict__ ln_b,
    const short* __restrict__ wF,    // [4][ W1c(9216) | W2c(9216) ] frag-ordered
    const float* __restrict__ b1,
    const float* __restrict__ b2)
{
    __shared__ short wbuf1[9216];      // 18 KB: current W1 frags
    __shared__ short wbuf2[2][9216];   // 36 KB: W2 double buffer
    __shared__ short h_s[128*104];     // 26.6 KB hidden

    const int t = threadIdx.x;
    const int lane = t & 63;
    const int wv = t >> 6;             // 0..3
    const int l15 = lane & 15, lhi = (lane >> 4) & 3;
    const size_t tok0 = (size_t)blockIdx.x * 128 + wv*32;

    // ---- prologue: issue chunk-0 stage (both halves), LN under latency ----
    if (wv < 2) {
        #pragma unroll
        for (int k = 0; k < 9; ++k) {
            int f = k*2 + wv;
            gload_lds16(wF + f*512 + lane*8, &wbuf1[f*512]);
        }
    } else {
        #pragma unroll
        for (int k = 0; k < 9; ++k) {
            int f = k*2 + (wv - 2);
            gload_lds16(wF + 9216 + f*512 + lane*8, &wbuf2[0][f*512]);
        }
    }

    // ---- LN -> y A-fragments in registers (shfl over lhi groups) ----
    bf16x8 y[2][3];
    {
        float g[24], bb[24];
        #pragma unroll
        for (int ks = 0; ks < 3; ++ks)
            #pragma unroll
            for (int q = 0; q < 2; ++q) {
                float4 gv = *reinterpret_cast<const float4*>(ln_g + ks*32 + lhi*8 + q*4);
                float4 bv = *reinterpret_cast<const float4*>(ln_b + ks*32 + lhi*8 + q*4);
                g[ks*8+q*4+0]=gv.x; g[ks*8+q*4+1]=gv.y; g[ks*8+q*4+2]=gv.z; g[ks*8+q*4+3]=gv.w;
                bb[ks*8+q*4+0]=bv.x; bb[ks*8+q*4+1]=bv.y; bb[ks*8+q*4+2]=bv.z; bb[ks*8+q*4+3]=bv.w;
            }
        #pragma unroll
        for (int m = 0; m < 2; ++m) {
            const float* src = xp + (tok0 + m*16 + l15)*96 + lhi*8;
            float v[24];
            #pragma unroll
            for (int ks = 0; ks < 3; ++ks) {
                float4 a0 = *reinterpret_cast<const float4*>(src + ks*32);
                float4 a1 = *reinterpret_cast<const float4*>(src + ks*32 + 4);
                v[ks*8+0]=a0.x; v[ks*8+1]=a0.y; v[ks*8+2]=a0.z; v[ks*8+3]=a0.w;
                v[ks*8+4]=a1.x; v[ks*8+5]=a1.y; v[ks*8+6]=a1.z; v[ks*8+7]=a1.w;
            }
            float s = 0.f, s2 = 0.f;
            #pragma unroll
            for (int j = 0; j < 24; ++j) { s += v[j]; s2 += v[j]*v[j]; }
            s  += __shfl_xor(s, 16);  s  += __shfl_xor(s, 32);
            s2 += __shfl_xor(s2, 16); s2 += __shfl_xor(s2, 32);
            float mu = s * (1.f/96.f);
            float var = s2 * (1.f/96.f) - mu*mu;
            float rs = rsqrtf(var + 1e-5f);
            #pragma unroll
            for (int ks = 0; ks < 3; ++ks) {
                bf16x8 yy;
                #pragma unroll
                for (int j = 0; j < 8; ++j)
                    yy[j] = f2bf((v[ks*8+j] - mu)*rs*g[ks*8+j] + bb[ks*8+j]);
                y[m][ks] = yy;
            }
        }
    }

    f32x4 acc2[2][6];
    #pragma unroll
    for (int m = 0; m < 2; ++m)
        #pragma unroll
        for (int n = 0; n < 6; ++n)
            { acc2[m][n][0]=0.f; acc2[m][n][1]=0.f; acc2[m][n][2]=0.f; acc2[m][n][3]=0.f; }

    asm volatile("s_waitcnt vmcnt(0)" ::: "memory");
    __syncthreads();   // chunk 0 staged (both halves)

    for (int c = 0; c < 4; ++c) {
        const int p = c & 1;
        // issue W2(c+1) into other buffer; last reader of it (FF2(c-1))
        // completed before the end-of-iter barrier of c-1.
        if (c < 3 && wv >= 2) {
            #pragma unroll
            for (int k = 0; k < 9; ++k) {
                int f = k*2 + (wv - 2);
                gload_lds16(wF + (c + 1)*18432 + 9216 + f*512 + lane*8,
                            &wbuf2[p ^ 1][f*512]);
            }
        }

        // ---- FF1: acc1 = y @ W1c ----
        f32x4 acc1[2][6];
        #pragma unroll
        for (int m = 0; m < 2; ++m)
            #pragma unroll
            for (int n = 0; n < 6; ++n)
                { acc1[m][n][0]=0.f; acc1[m][n][1]=0.f; acc1[m][n][2]=0.f; acc1[m][n][3]=0.f; }
        #pragma unroll
        for (int ks = 0; ks < 3; ++ks)
            #pragma unroll
            for (int n = 0; n < 6; ++n) {
                bf16x8 bw = *reinterpret_cast<const bf16x8*>(
                    &wbuf1[(ks*6 + n)*512 + lane*8]);
                #pragma unroll
                for (int m = 0; m < 2; ++m)
                    acc1[m][n] = __builtin_amdgcn_mfma_f32_16x16x32_bf16(
                        y[m][ks], bw, acc1[m][n], 0, 0, 0);
            }

        __syncthreads();   // all waves done reading W1c
        if (c < 3 && wv < 2) {
            #pragma unroll
            for (int k = 0; k < 9; ++k) {
                int f = k*2 + wv;
                gload_lds16(wF + (c + 1)*18432 + f*512 + lane*8, &wbuf1[f*512]);
            }
        }

        // ---- bias + GELU -> h_s (own-wave rows) ----
        #pragma unroll
        for (int n = 0; n < 6; ++n) {
            float bias = b1[c*96 + n*16 + l15];
            #pragma unroll
            for (int m = 0; m < 2; ++m)
                #pragma unroll
                for (int r = 0; r < 4; ++r) {
                    float hv = gelu_tanh(acc1[m][n][r] + bias);
                    int row = wv*32 + m*16 + lhi*4 + r;
                    h_s[row*104 + n*16 + l15] = f2bf(hv);
                }
        }

        // ---- FF2 partial: acc2 += h @ W2c ----
        #pragma unroll
        for (int ks = 0; ks < 3; ++ks) {
            bf16x8 ah[2];
            #pragma unroll
            for (int m = 0; m < 2; ++m)
                ah[m] = *reinterpret_cast<const bf16x8*>(
                    &h_s[(wv*32 + m*16 + l15)*104 + ks*32 + lhi*8]);
            #pragma unroll
            for (int n = 0; n < 6; ++n) {
                bf16x8 bw = *reinterpret_cast<const bf16x8*>(
                    &wbuf2[p][(ks*6 + n)*512 + lane*8]);
                #pragma unroll
                for (int m = 0; m < 2; ++m)
                    acc2[m][n] = __builtin_amdgcn_mfma_f32_16x16x32_bf16(
                        ah[m], bw, acc2[m][n], 0, 0, 0);
            }
        }

        if (c < 3) {
            // each wave drains its OWN outstanding DMAs (w0-1: W1c+1, w2-3: W2c+1),
            // then barrier makes both visible to all.
            asm volatile("s_waitcnt vmcnt(0)" ::: "memory");
            __syncthreads();
        }
    }

    // ---- epilogue: xp += acc2 + b2 ----
    float b2v[6];
    #pragma unroll
    for (int n = 0; n < 6; ++n) b2v[n] = b2[n*16 + l15];
    #pragma unroll
    for (int m = 0; m < 2; ++m)
        #pragma unroll
        for (int r = 0; r < 4; ++r) {
            float* dst = xp + (tok0 + m*16 + lhi*4 + r)*96 + l15;
            #pragma unroll
            for (int n = 0; n < 6; ++n)
                dst[n*16] += acc2[m][n][r] + b2v[n];
        }
}

// ------------- (b,112,112,96) -> (b,96,112,112) fp32 -----------------------
__global__ __launch_bounds__(256) void out_kernel(
    const float* __restrict__ xp, float* __restrict__ out)
{
    __shared__ float tile[64*100];
    const int t = threadIdx.x;
    const int b = blockIdx.y;
    const int p0 = blockIdx.x * 64;
    for (int e = t; e < 64*24; e += 256) {
        int r = e / 24, p = e % 24;
        *reinterpret_cast<float4*>(&tile[r*100 + p*4]) =
            *reinterpret_cast<const float4*>(xp + ((size_t)b*NPIX + p0 + r)*96 + p*4);
    }
    __syncthreads();
    for (int e = t; e < 96*64; e += 256) {
        int ch = e >> 6, p = e & 63;
        out[((size_t)(b*96 + ch))*NPIX + p0 + p] = tile[p*100 + ch];
    }
}

extern "C" void kernel_launch(void* const* d_in, const int* in_sizes, int n_in,
                              void* d_out, int out_size, void* d_ws, size_t ws_size,
                              hipStream_t stream)
{
    (void)in_sizes; (void)n_in; (void)out_size; (void)ws_size;
    const float* x     = (const float*)d_in[0];
    const float* pm_w  = (const float*)d_in[1];
    const float* pm_b  = (const float*)d_in[2];
    const float* ln1_g = (const float*)d_in[3];
    const float* ln1_b = (const float*)d_in[4];
    const float* qkv_w = (const float*)d_in[5];
    const float* pos   = (const float*)d_in[6];
    const float* out_w = (const float*)d_in[7];
    const float* out_b = (const float*)d_in[8];
    const float* ln2_g = (const float*)d_in[9];
    const float* ln2_b = (const float*)d_in[10];
    const float* ff1_w = (const float*)d_in[11];
    const float* ff1_b = (const float*)d_in[12];
    const float* ff2_w = (const float*)d_in[13];
    const float* ff2_b = (const float*)d_in[14];

    float* xp    = (float*)d_ws;
    short* wF_b  = (short*)(xp + (size_t)NTOK_TOTAL * 96);  // [2][73728] frag-ordered
    short* qkvT_b = wF_b + 147456;                          // [2][288][96]
    short* outT_b = qkvT_b + 2*288*96;                      // [2][96][96]

    prep_weights_kernel<<<864, 256, 0, stream>>>(ff1_w, ff2_w, qkv_w, out_w,
                                                 wF_b, qkvT_b, outT_b);
    patch_merge_kernel<<<dim3(7, 112, 16), 256, 0, stream>>>(x, pm_w, pm_b, xp);

    for (int L = 0; L < 2; ++L) {
        if (L == 0)
            attn_mfma_kernel<false><<<dim3(256, 16), 192, 0, stream>>>(
                xp, ln1_g, ln1_b, qkvT_b, pos, outT_b, out_b);
        else
            attn_mfma_kernel<true><<<dim3(256, 16), 192, 0, stream>>>(
                xp, ln1_g + 96, ln1_b + 96, qkvT_b + 27648, pos + 169,
                outT_b + 9216, out_b + 96);
        ff_mfma_kernel<<<1568, 256, 0, stream>>>(
            xp, ln2_g + L*96, ln2_b + L*96,
            wF_b + (size_t)L*73728, ff1_b + L*384, ff2_b + L*96);
    }
    out_kernel<<<dim3(196, 16), 256, 0, stream>>>(xp, (float*)d_out);
}

// Round 19
// 506.205 us; speedup vs baseline: 1.4012x; 1.4012x over previous
//
#include <hip/hip_runtime.h>
#include <hip/hip_bf16.h>

#define HW 112
#define NPIX (HW*HW)            // 12544
#define NTOK_TOTAL (16*NPIX)    // 200704
#define SCALE_ATTN 0.17677669529663689f

typedef short bf16x8 __attribute__((ext_vector_type(8)));
typedef float f32x4 __attribute__((ext_vector_type(4)));

__device__ __forceinline__ short f2bf(float f) {
    __hip_bfloat16 h = __float2bfloat16(f);
    return *reinterpret_cast<short*>(&h);
}

// tanh-form GELU: x * sigmoid(1.5957691*x + 0.0713548*x^3); |err| ~3e-4
__device__ __forceinline__ float gelu_tanh(float x) {
    float t  = x * x;
    float m1 = fmaf(0.071354816f, t, 1.5957691f);
    float e  = __expf(x * m1);
    float r  = __builtin_amdgcn_rcpf(e + 1.0f);
    return fmaf(-x, r, x);
}

// async global->LDS, 16B per lane; lds dest must be wave-uniform base
__device__ __forceinline__ void gload_lds16(const short* g, short* l) {
    __builtin_amdgcn_global_load_lds(
        (__attribute__((address_space(1))) void*)g,
        (__attribute__((address_space(3))) void*)l,
        16, 0, 0);
}

// ---------------- patch merging: x (16,3,448,448) -> xp (16,112,112,96) ----
// v1 (known good): one block per 16 output pixels.
__global__ __launch_bounds__(256) void patch_merge_kernel(
    const float* __restrict__ x, const float* __restrict__ pm_w,
    const float* __restrict__ pm_b, float* __restrict__ xp)
{
    __shared__ float w_lds[48*96];
    __shared__ float in_lds[16*52];
    __shared__ float b_lds[96];
    const int t = threadIdx.x;
    const int jt = blockIdx.x, i = blockIdx.y, b = blockIdx.z;
    const int j0 = jt * 16;

    for (int e = t; e < 48*96; e += 256) w_lds[e] = pm_w[e];
    if (t < 96) b_lds[t] = pm_b[t];
    for (int e = t; e < 768; e += 256) {
        int r = e >> 6, col = e & 63;
        int c = r >> 2, kh = r & 3;
        float v = x[(((size_t)(b*3 + c))*448 + (4*i + kh))*448 + 4*j0 + col];
        in_lds[(col >> 2)*52 + c*16 + kh*4 + (col & 3)] = v;
    }
    __syncthreads();
    for (int e = t; e < 16*96; e += 256) {
        int pos = e / 96, ch = e % 96;
        float acc = b_lds[ch];
        #pragma unroll
        for (int k = 0; k < 48; ++k)
            acc = fmaf(in_lds[pos*52 + k], w_lds[k*96 + ch], acc);
        xp[((size_t)((b*HW + i)*HW) + j0 + pos)*96 + ch] = acc;
    }
}

// ------------- weight prep -------------------------------------------------
// FF weights -> fragment-ordered wF[2][4][ W1c(9216) | W2c(9216) ]
// qkvT [2][288][96] (q cols pre-scaled by SCALE_ATTN), outT [2][96][96]
__global__ __launch_bounds__(256) void prep_weights_kernel(
    const float* __restrict__ ff1, const float* __restrict__ ff2,
    const float* __restrict__ qkv_w, const float* __restrict__ out_w,
    short* __restrict__ wF,
    short* __restrict__ qkvT, short* __restrict__ outT)
{
    int i = blockIdx.x * 256 + threadIdx.x;
    if (i < 147456) {
        int l = i / 73728, r = i % 73728;
        int c = r / 18432, r2 = r % 18432;
        int half = r2 / 9216, r3 = r2 % 9216;
        int f = r3 / 512, L = (r3 % 512) / 8, j = r3 % 8;
        int ks = f / 6, n = f % 6;
        float val;
        if (half == 0) {
            int k  = ks*32 + (L >> 4)*8 + j;       // 0..95
            int ng = c*96 + n*16 + (L & 15);       // 0..383
            val = ff1[(size_t)l*36864 + (size_t)k*384 + ng];
        } else {
            int kg = c*96 + ks*32 + (L >> 4)*8 + j; // 0..383
            int ng = n*16 + (L & 15);               // 0..95
            val = ff2[(size_t)l*36864 + (size_t)kg*96 + ng];
        }
        wF[i] = f2bf(val);
    } else if (i < 202752) {
        int j = i - 147456;
        int l = j / 27648, r = j % 27648, n = r / 96, k = r % 96;
        float v = qkv_w[(size_t)l*27648 + k*288 + n];
        if (n < 96) v *= SCALE_ATTN;   // fold attention scale into W_q
        qkvT[j] = f2bf(v);
    } else if (i < 221184) {
        int j = i - 202752;
        int l = j / 9216, r = j % 9216, n = r / 96, k = r % 96;
        outT[j] = f2bf(out_w[(size_t)l*9216 + k*96 + n]);
    }
}

// ---- fused LN1 + qkv + window attention + out-proj + residual (bf16 MFMA) --
template<bool SHIFTED>
__global__ __launch_bounds__(192) void attn_mfma_kernel(
    float* __restrict__ xp,
    const float* __restrict__ ln_g, const float* __restrict__ ln_b,
    const short* __restrict__ qkvT,
    const float* __restrict__ pos_tab,
    const short* __restrict__ outT,
    const float* __restrict__ out_b)
{
    __shared__ short bufA[13824];
    __shared__ short qk_s[13824];
    __shared__ short vT_s[6912];
    __shared__ float pos_l[169];
    __shared__ float ob_s[96];
    __shared__ float lng[96], lnb[96];

    const int t = threadIdx.x;
    const int lane = t & 63;
    const int h = t >> 6;
    const int l15 = lane & 15, lhi = lane >> 4;
    const int wh = blockIdx.x >> 4, ww = blockIdx.x & 15;
    const int b = blockIdx.y;
    const int SH = SHIFTED ? 3 : 0;

    if (t < 169) pos_l[t] = pos_tab[t];
    if (t < 96) { lng[t] = ln_g[t]; lnb[t] = ln_b[t]; ob_s[t] = out_b[t]; }
    __syncthreads();

    {
        const int part = t & 3;
        for (int row = t >> 2; row < 49; row += 48) {
            int ti = (row*37) >> 8, tj = row - ti*7;
            int gi = wh*7 + ti + SH; if (gi >= HW) gi -= HW;
            int gj = ww*7 + tj + SH; if (gj >= HW) gj -= HW;
            const float* src = xp + ((size_t)((b*HW + gi)*HW + gj))*96 + part*24;
            float v[24];
            #pragma unroll
            for (int q4 = 0; q4 < 6; ++q4) {
                float4 vv = *reinterpret_cast<const float4*>(src + q4*4);
                v[q4*4+0]=vv.x; v[q4*4+1]=vv.y; v[q4*4+2]=vv.z; v[q4*4+3]=vv.w;
            }
            float s = 0.f, s2 = 0.f;
            #pragma unroll
            for (int j = 0; j < 24; ++j) { s += v[j]; s2 += v[j]*v[j]; }
            s  += __shfl_xor(s, 1);  s  += __shfl_xor(s, 2);
            s2 += __shfl_xor(s2, 1); s2 += __shfl_xor(s2, 2);
            float mu = s * (1.f/96.f);
            float var = s2 * (1.f/96.f) - mu*mu;
            float rs = rsqrtf(var + 1e-5f);
            unsigned* yw = reinterpret_cast<unsigned*>(bufA) + row*52 + part*12;
            #pragma unroll
            for (int j = 0; j < 12; ++j) {
                int c = part*24 + 2*j;
                float lo = (v[2*j]   - mu)*rs*lng[c]   + lnb[c];
                float hi = (v[2*j+1] - mu)*rs*lng[c+1] + lnb[c+1];
                yw[j] = (unsigned)(unsigned short)f2bf(lo) |
                        ((unsigned)(unsigned short)f2bf(hi) << 16);
            }
        }
        for (int e = t; e < 15*52; e += 192)
            reinterpret_cast<unsigned*>(bufA)[(49 + e/52)*52 + e%52] = 0u;
    }
    __syncthreads();

    {
        f32x4 acc[3][2][4];
        #pragma unroll
        for (int p = 0; p < 3; ++p)
            #pragma unroll
            for (int s = 0; s < 2; ++s)
                #pragma unroll
                for (int m = 0; m < 4; ++m)
                    { acc[p][s][m][0]=0.f; acc[p][s][m][1]=0.f; acc[p][s][m][2]=0.f; acc[p][s][m][3]=0.f; }
        #pragma unroll
        for (int ks = 0; ks < 3; ++ks) {
            bf16x8 a[4];
            #pragma unroll
            for (int m = 0; m < 4; ++m)
                a[m] = *reinterpret_cast<const bf16x8*>(&bufA[(m*16 + l15)*104 + ks*32 + lhi*8]);
            #pragma unroll
            for (int p = 0; p < 3; ++p)
                #pragma unroll
                for (int s = 0; s < 2; ++s) {
                    bf16x8 bf = *reinterpret_cast<const bf16x8*>(
                        qkvT + (p*96 + h*32 + s*16 + l15)*96 + ks*32 + lhi*8);
                    #pragma unroll
                    for (int m = 0; m < 4; ++m)
                        acc[p][s][m] = __builtin_amdgcn_mfma_f32_16x16x32_bf16(
                            a[m], bf, acc[p][s][m], 0, 0, 0);
                }
        }
        #pragma unroll
        for (int p = 0; p < 3; ++p)
            #pragma unroll
            for (int s = 0; s < 2; ++s)
                #pragma unroll
                for (int m = 0; m < 4; ++m)
                    #pragma unroll
                    for (int r = 0; r < 4; ++r) {
                        int tok = m*16 + lhi*4 + r;
                        int c = s*16 + l15;
                        short val = f2bf(acc[p][s][m][r]);
                        if (p == 0)      qk_s[h*4608 + tok*72 + c] = val;
                        else if (p == 1) qk_s[h*4608 + tok*72 + 32 + c] = val;
                        else             vT_s[h*2304 + c*72 + tok] = val;
                    }
    }
    __syncthreads();

    float pv[4][4][4];
    {
        f32x4 sacc[4][4];
        #pragma unroll
        for (int m = 0; m < 4; ++m)
            #pragma unroll
            for (int n = 0; n < 4; ++n)
                { sacc[m][n][0]=0.f; sacc[m][n][1]=0.f; sacc[m][n][2]=0.f; sacc[m][n][3]=0.f; }
        bf16x8 aq[4], bk[4];
        #pragma unroll
        for (int m = 0; m < 4; ++m)
            aq[m] = *reinterpret_cast<const bf16x8*>(&qk_s[h*4608 + (m*16 + l15)*72 + lhi*8]);
        #pragma unroll
        for (int n = 0; n < 4; ++n)
            bk[n] = *reinterpret_cast<const bf16x8*>(&qk_s[h*4608 + (n*16 + l15)*72 + 32 + lhi*8]);
        #pragma unroll
        for (int m = 0; m < 4; ++m)
            #pragma unroll
            for (int n = 0; n < 4; ++n)
                sacc[m][n] = __builtin_amdgcn_mfma_f32_16x16x32_bf16(aq[m], bk[n], sacc[m][n], 0, 0, 0);

        #pragma unroll
        for (int m = 0; m < 4; ++m)
            #pragma unroll
            for (int n = 0; n < 4; ++n)
                #pragma unroll
                for (int r = 0; r < 4; ++r) {
                    int i = m*16 + lhi*4 + r, j = n*16 + l15;
                    float v;
                    if (i >= 49 || j >= 49) v = -1e30f;
                    else {
                        int xi = (i*37) >> 8, yi = i - xi*7;
                        int xj = (j*37) >> 8, yj = j - xj*7;
                        v = sacc[m][n][r] + pos_l[(xj - xi + 6)*13 + (yj - yi + 6)];
                        if (SHIFTED) {
                            if (wh == 15 && ((xi >= 4) != (xj >= 4))) v = -1e30f;
                            if (ww == 15 && ((yi >= 4) != (yj >= 4))) v = -1e30f;
                        }
                    }
                    pv[m][n][r] = v;
                }
    }
    #pragma unroll
    for (int m = 0; m < 4; ++m)
        #pragma unroll
        for (int r = 0; r < 4; ++r) {
            float mx = fmaxf(fmaxf(pv[m][0][r], pv[m][1][r]), fmaxf(pv[m][2][r], pv[m][3][r]));
            mx = fmaxf(mx, __shfl_xor(mx, 1)); mx = fmaxf(mx, __shfl_xor(mx, 2));
            mx = fmaxf(mx, __shfl_xor(mx, 4)); mx = fmaxf(mx, __shfl_xor(mx, 8));
            float e0 = __expf(pv[m][0][r] - mx), e1 = __expf(pv[m][1][r] - mx);
            float e2 = __expf(pv[m][2][r] - mx), e3 = __expf(pv[m][3][r] - mx);
            float s = e0 + e1 + e2 + e3;
            s += __shfl_xor(s, 1); s += __shfl_xor(s, 2);
            s += __shfl_xor(s, 4); s += __shfl_xor(s, 8);
            float inv = 1.f / s;
            pv[m][0][r] = e0*inv; pv[m][1][r] = e1*inv;
            pv[m][2][r] = e2*inv; pv[m][3][r] = e3*inv;
        }
    #pragma unroll
    for (int m = 0; m < 4; ++m)
        #pragma unroll
        for (int n = 0; n < 4; ++n)
            #pragma unroll
            for (int r = 0; r < 4; ++r)
                bufA[h*4608 + (m*16 + lhi*4 + r)*72 + n*16 + l15] = f2bf(pv[m][n][r]);

    f32x4 oacc[2][4];
    #pragma unroll
    for (int n = 0; n < 2; ++n)
        #pragma unroll
        for (int m = 0; m < 4; ++m)
            { oacc[n][m][0]=0.f; oacc[n][m][1]=0.f; oacc[n][m][2]=0.f; oacc[n][m][3]=0.f; }
    #pragma unroll
    for (int ks = 0; ks < 2; ++ks) {
        bf16x8 ap[4], bv[2];
        #pragma unroll
        for (int m = 0; m < 4; ++m)
            ap[m] = *reinterpret_cast<const bf16x8*>(&bufA[h*4608 + (m*16 + l15)*72 + ks*32 + lhi*8]);
        #pragma unroll
        for (int n = 0; n < 2; ++n)
            bv[n] = *reinterpret_cast<const bf16x8*>(&vT_s[h*2304 + (n*16 + l15)*72 + ks*32 + lhi*8]);
        #pragma unroll
        for (int n = 0; n < 2; ++n)
            #pragma unroll
            for (int m = 0; m < 4; ++m)
                oacc[n][m] = __builtin_amdgcn_mfma_f32_16x16x32_bf16(ap[m], bv[n], oacc[n][m], 0, 0, 0);
    }
    __syncthreads();
    #pragma unroll
    for (int n = 0; n < 2; ++n)
        #pragma unroll
        for (int m = 0; m < 4; ++m)
            #pragma unroll
            for (int r = 0; r < 4; ++r)
                bufA[(m*16 + lhi*4 + r)*104 + h*32 + n*16 + l15] = f2bf(oacc[n][m][r]);
    __syncthreads();

    {
        f32x4 pacc[2][4];
        #pragma unroll
        for (int n = 0; n < 2; ++n)
            #pragma unroll
            for (int m = 0; m < 4; ++m)
                { pacc[n][m][0]=0.f; pacc[n][m][1]=0.f; pacc[n][m][2]=0.f; pacc[n][m][3]=0.f; }
        #pragma unroll
        for (int ks = 0; ks < 3; ++ks) {
            bf16x8 ao[4], bw[2];
            #pragma unroll
            for (int m = 0; m < 4; ++m)
                ao[m] = *reinterpret_cast<const bf16x8*>(&bufA[(m*16 + l15)*104 + ks*32 + lhi*8]);
            #pragma unroll
            for (int n = 0; n < 2; ++n)
                bw[n] = *reinterpret_cast<const bf16x8*>(
                    outT + ((h*2 + n)*16 + l15)*96 + ks*32 + lhi*8);
            #pragma unroll
            for (int n = 0; n < 2; ++n)
                #pragma unroll
                for (int m = 0; m < 4; ++m)
                    pacc[n][m] = __builtin_amdgcn_mfma_f32_16x16x32_bf16(ao[m], bw[n], pacc[n][m], 0, 0, 0);
        }
        #pragma unroll
        for (int m = 0; m < 4; ++m)
            #pragma unroll
            for (int r = 0; r < 4; ++r) {
                int tok = m*16 + lhi*4 + r;
                if (tok < 49) {
                    int ti = (tok*37) >> 8, tj = tok - ti*7;
                    int gi = wh*7 + ti + SH; if (gi >= HW) gi -= HW;
                    int gj = ww*7 + tj + SH; if (gj >= HW) gj -= HW;
                    float* dst = xp + ((size_t)((b*HW + gi)*HW + gj))*96;
                    #pragma unroll
                    for (int n = 0; n < 2; ++n) {
                        int ch = (h*2 + n)*16 + l15;
                        dst[ch] += pacc[n][m][r] + ob_s[ch];
                    }
                }
            }
    }
}

// ------------- fused LN2 + FF1 + GELU + FF2 + residual (bf16 MFMA v7) ------
// 4 waves / 128 tokens; split staging (waves 0-1 own W1, waves 2-3 own W2),
// W2 double-buffered; all DMA overlapped under compute (T3/T4-min).
__global__ __launch_bounds__(256) void ff_mfma_kernel(
    float* __restrict__ xp,
    const float* __restrict__ ln_g, const float* __restrict__ ln_b,
    const short* __restrict__ wF,    // [4][ W1c(9216) | W2c(9216) ] frag-ordered
    const float* __restrict__ b1,
    const float* __restrict__ b2)
{
    __shared__ short wbuf1[9216];      // 18 KB: current W1 frags
    __shared__ short wbuf2[2][9216];   // 36 KB: W2 double buffer
    __shared__ short h_s[128*104];     // 26.6 KB hidden

    const int t = threadIdx.x;
    const int lane = t & 63;
    const int wv = t >> 6;             // 0..3
    const int l15 = lane & 15, lhi = (lane >> 4) & 3;
    const size_t tok0 = (size_t)blockIdx.x * 128 + wv*32;

    // ---- prologue: issue chunk-0 stage (both halves), LN under latency ----
    if (wv < 2) {
        #pragma unroll
        for (int k = 0; k < 9; ++k) {
            int f = k*2 + wv;
            gload_lds16(wF + f*512 + lane*8, &wbuf1[f*512]);
        }
    } else {
        #pragma unroll
        for (int k = 0; k < 9; ++k) {
            int f = k*2 + (wv - 2);
            gload_lds16(wF + 9216 + f*512 + lane*8, &wbuf2[0][f*512]);
        }
    }

    // ---- LN -> y A-fragments in registers (shfl over lhi groups) ----
    bf16x8 y[2][3];
    {
        float g[24], bb[24];
        #pragma unroll
        for (int ks = 0; ks < 3; ++ks)
            #pragma unroll
            for (int q = 0; q < 2; ++q) {
                float4 gv = *reinterpret_cast<const float4*>(ln_g + ks*32 + lhi*8 + q*4);
                float4 bv = *reinterpret_cast<const float4*>(ln_b + ks*32 + lhi*8 + q*4);
                g[ks*8+q*4+0]=gv.x; g[ks*8+q*4+1]=gv.y; g[ks*8+q*4+2]=gv.z; g[ks*8+q*4+3]=gv.w;
                bb[ks*8+q*4+0]=bv.x; bb[ks*8+q*4+1]=bv.y; bb[ks*8+q*4+2]=bv.z; bb[ks*8+q*4+3]=bv.w;
            }
        #pragma unroll
        for (int m = 0; m < 2; ++m) {
            const float* src = xp + (tok0 + m*16 + l15)*96 + lhi*8;
            float v[24];
            #pragma unroll
            for (int ks = 0; ks < 3; ++ks) {
                float4 a0 = *reinterpret_cast<const float4*>(src + ks*32);
                float4 a1 = *reinterpret_cast<const float4*>(src + ks*32 + 4);
                v[ks*8+0]=a0.x; v[ks*8+1]=a0.y; v[ks*8+2]=a0.z; v[ks*8+3]=a0.w;
                v[ks*8+4]=a1.x; v[ks*8+5]=a1.y; v[ks*8+6]=a1.z; v[ks*8+7]=a1.w;
            }
            float s = 0.f, s2 = 0.f;
            #pragma unroll
            for (int j = 0; j < 24; ++j) { s += v[j]; s2 += v[j]*v[j]; }
            s  += __shfl_xor(s, 16);  s  += __shfl_xor(s, 32);
            s2 += __shfl_xor(s2, 16); s2 += __shfl_xor(s2, 32);
            float mu = s * (1.f/96.f);
            float var = s2 * (1.f/96.f) - mu*mu;
            float rs = rsqrtf(var + 1e-5f);
            #pragma unroll
            for (int ks = 0; ks < 3; ++ks) {
                bf16x8 yy;
                #pragma unroll
                for (int j = 0; j < 8; ++j)
                    yy[j] = f2bf((v[ks*8+j] - mu)*rs*g[ks*8+j] + bb[ks*8+j]);
                y[m][ks] = yy;
            }
        }
    }

    f32x4 acc2[2][6];
    #pragma unroll
    for (int m = 0; m < 2; ++m)
        #pragma unroll
        for (int n = 0; n < 6; ++n)
            { acc2[m][n][0]=0.f; acc2[m][n][1]=0.f; acc2[m][n][2]=0.f; acc2[m][n][3]=0.f; }

    asm volatile("s_waitcnt vmcnt(0)" ::: "memory");
    __syncthreads();   // chunk 0 staged (both halves)

    for (int c = 0; c < 4; ++c) {
        const int p = c & 1;
        // issue W2(c+1) into other buffer; last reader of it (FF2(c-1))
        // completed before the end-of-iter barrier of c-1.
        if (c < 3 && wv >= 2) {
            #pragma unroll
            for (int k = 0; k < 9; ++k) {
                int f = k*2 + (wv - 2);
                gload_lds16(wF + (c + 1)*18432 + 9216 + f*512 + lane*8,
                            &wbuf2[p ^ 1][f*512]);
            }
        }

        // ---- FF1: acc1 = y @ W1c ----
        f32x4 acc1[2][6];
        #pragma unroll
        for (int m = 0; m < 2; ++m)
            #pragma unroll
            for (int n = 0; n < 6; ++n)
                { acc1[m][n][0]=0.f; acc1[m][n][1]=0.f; acc1[m][n][2]=0.f; acc1[m][n][3]=0.f; }
        #pragma unroll
        for (int ks = 0; ks < 3; ++ks)
            #pragma unroll
            for (int n = 0; n < 6; ++n) {
                bf16x8 bw = *reinterpret_cast<const bf16x8*>(
                    &wbuf1[(ks*6 + n)*512 + lane*8]);
                #pragma unroll
                for (int m = 0; m < 2; ++m)
                    acc1[m][n] = __builtin_amdgcn_mfma_f32_16x16x32_bf16(
                        y[m][ks], bw, acc1[m][n], 0, 0, 0);
            }

        __syncthreads();   // all waves done reading W1c
        if (c < 3 && wv < 2) {
            #pragma unroll
            for (int k = 0; k < 9; ++k) {
                int f = k*2 + wv;
                gload_lds16(wF + (c + 1)*18432 + f*512 + lane*8, &wbuf1[f*512]);
            }
        }

        // ---- bias + GELU -> h_s (own-wave rows) ----
        #pragma unroll
        for (int n = 0; n < 6; ++n) {
            float bias = b1[c*96 + n*16 + l15];
            #pragma unroll
            for (int m = 0; m < 2; ++m)
                #pragma unroll
                for (int r = 0; r < 4; ++r) {
                    float hv = gelu_tanh(acc1[m][n][r] + bias);
                    int row = wv*32 + m*16 + lhi*4 + r;
                    h_s[row*104 + n*16 + l15] = f2bf(hv);
                }
        }

        // ---- FF2 partial: acc2 += h @ W2c ----
        #pragma unroll
        for (int ks = 0; ks < 3; ++ks) {
            bf16x8 ah[2];
            #pragma unroll
            for (int m = 0; m < 2; ++m)
                ah[m] = *reinterpret_cast<const bf16x8*>(
                    &h_s[(wv*32 + m*16 + l15)*104 + ks*32 + lhi*8]);
            #pragma unroll
            for (int n = 0; n < 6; ++n) {
                bf16x8 bw = *reinterpret_cast<const bf16x8*>(
                    &wbuf2[p][(ks*6 + n)*512 + lane*8]);
                #pragma unroll
                for (int m = 0; m < 2; ++m)
                    acc2[m][n] = __builtin_amdgcn_mfma_f32_16x16x32_bf16(
                        ah[m], bw, acc2[m][n], 0, 0, 0);
            }
        }

        if (c < 3) {
            // each wave drains its OWN outstanding DMAs (w0-1: W1c+1, w2-3: W2c+1),
            // then barrier makes both visible to all.
            asm volatile("s_waitcnt vmcnt(0)" ::: "memory");
            __syncthreads();
        }
    }

    // ---- epilogue: xp += acc2 + b2 ----
    float b2v[6];
    #pragma unroll
    for (int n = 0; n < 6; ++n) b2v[n] = b2[n*16 + l15];
    #pragma unroll
    for (int m = 0; m < 2; ++m)
        #pragma unroll
        for (int r = 0; r < 4; ++r) {
            float* dst = xp + (tok0 + m*16 + lhi*4 + r)*96 + l15;
            #pragma unroll
            for (int n = 0; n < 6; ++n)
                dst[n*16] += acc2[m][n][r] + b2v[n];
        }
}

// ------------- (b,112,112,96) -> (b,96,112,112) fp32 -----------------------
__global__ __launch_bounds__(256) void out_kernel(
    const float* __restrict__ xp, float* __restrict__ out)
{
    __shared__ float tile[64*100];
    const int t = threadIdx.x;
    const int b = blockIdx.y;
    const int p0 = blockIdx.x * 64;
    for (int e = t; e < 64*24; e += 256) {
        int r = e / 24, p = e % 24;
        *reinterpret_cast<float4*>(&tile[r*100 + p*4]) =
            *reinterpret_cast<const float4*>(xp + ((size_t)b*NPIX + p0 + r)*96 + p*4);
    }
    __syncthreads();
    for (int e = t; e < 96*64; e += 256) {
        int ch = e >> 6, p = e & 63;
        out[((size_t)(b*96 + ch))*NPIX + p0 + p] = tile[p*100 + ch];
    }
}

extern "C" void kernel_launch(void* const* d_in, const int* in_sizes, int n_in,
                              void* d_out, int out_size, void* d_ws, size_t ws_size,
                              hipStream_t stream)
{
    (void)in_sizes; (void)n_in; (void)out_size; (void)ws_size;
    const float* x     = (const float*)d_in[0];
    const float* pm_w  = (const float*)d_in[1];
    const float* pm_b  = (const float*)d_in[2];
    const float* ln1_g = (const float*)d_in[3];
    const float* ln1_b = (const float*)d_in[4];
    const float* qkv_w = (const float*)d_in[5];
    const float* pos   = (const float*)d_in[6];
    const float* out_w = (const float*)d_in[7];
    const float* out_b = (const float*)d_in[8];
    const float* ln2_g = (const float*)d_in[9];
    const float* ln2_b = (const float*)d_in[10];
    const float* ff1_w = (const float*)d_in[11];
    const float* ff1_b = (const float*)d_in[12];
    const float* ff2_w = (const float*)d_in[13];
    const float* ff2_b = (const float*)d_in[14];

    float* xp    = (float*)d_ws;
    short* wF_b  = (short*)(xp + (size_t)NTOK_TOTAL * 96);  // [2][73728] frag-ordered
    short* qkvT_b = wF_b + 147456;                          // [2][288][96]
    short* outT_b = qkvT_b + 2*288*96;                      // [2][96][96]

    prep_weights_kernel<<<864, 256, 0, stream>>>(ff1_w, ff2_w, qkv_w, out_w,
                                                 wF_b, qkvT_b, outT_b);
    patch_merge_kernel<<<dim3(7, 112, 16), 256, 0, stream>>>(x, pm_w, pm_b, xp);

    for (int L = 0; L < 2; ++L) {
        if (L == 0)
            attn_mfma_kernel<false><<<dim3(256, 16), 192, 0, stream>>>(
                xp, ln1_g, ln1_b, qkvT_b, pos, outT_b, out_b);
        else
            attn_mfma_kernel<true><<<dim3(256, 16), 192, 0, stream>>>(
                xp, ln1_g + 96, ln1_b + 96, qkvT_b + 27648, pos + 169,
                outT_b + 9216, out_b + 96);
        ff_mfma_kernel<<<1568, 256, 0, stream>>>(
            xp, ln2_g + L*96, ln2_b + L*96,
            wF_b + (size_t)L*73728, ff1_b + L*384, ff2_b + L*96);
    }
    out_kernel<<<dim3(196, 16), 256, 0, stream>>>(xp, (float*)d_out);
}